// Round 6
// baseline (1360.684 us; speedup 1.0000x reference)
//
#include <hip/hip_runtime.h>
#include <hip/hip_bf16.h>
#include <float.h>

#define BB 8
#define NN 2048
#define KK 20
#define KROWS 8
#define BROWS 4   // rows per extraction batch (pdl resident)

static constexpr float BN_INV_F = 0.9999950000374997f;  // 1/sqrt(1+1e-5)

typedef __attribute__((ext_vector_type(4))) float f32x4;
typedef __attribute__((ext_vector_type(2))) float f32x2;
typedef __attribute__((ext_vector_type(8))) short s16x8;

__device__ __forceinline__ unsigned short f2bf(float f) {
    __hip_bfloat16 h = __float2bfloat16(f);
    return __builtin_bit_cast(unsigned short, h);
}
__device__ __forceinline__ float bf2f(unsigned short u) {
    unsigned int v = ((unsigned int)u) << 16;
    return __builtin_bit_cast(float, v);
}
// monotone f32 -> u32 (order-preserving for all floats)
__device__ __forceinline__ unsigned mono(float f) {
    unsigned b = __builtin_bit_cast(unsigned, f);
    return b ^ (unsigned)(((int)b >> 31) | 0x80000000);
}

// ---------------- split f32 -> bf16 hi/lo ----------------
__global__ void split_kernel(const float* __restrict__ w, unsigned short* __restrict__ hi,
                             unsigned short* __restrict__ lo, int n) {
    int t = blockIdx.x * blockDim.x + threadIdx.x;
    if (t >= n) return;
    float v = w[t];
    unsigned short h = f2bf(v);
    hi[t] = h;
    lo[t] = f2bf(v - bf2f(h));
}

// ---------------- squared norms: xx[b][n] = sum_c x[b][c][n]^2 ----------------
__global__ void sqnorm_kernel(const float* __restrict__ x, float* __restrict__ xx, int C) {
    int t = blockIdx.x * blockDim.x + threadIdx.x;
    if (t >= BB * NN) return;
    int b = t / NN, n = t % NN;
    const float* xb = x + (size_t)b * C * NN + n;
    float s = 0.f;
    for (int c = 0; c < C; ++c) {
        float v = xb[(size_t)c * NN];
        s += v * v;
    }
    xx[t] = s;
}

// ---------------- kNN: top-K of pd[n][m] = 2*inner - xx[n] - xx[m] ----------------
// pd phase: thread = 4 rows x 4 cols register block (2 batches of 4 rows).
// extraction: one wave per row; lane owns 32 elements in registers (ALL indices
// compile-time; swizzle lives in the load ADDRESS). Per k: one 6-step u64
// (value|~idx) max-butterfly; winner invalidates via unrolled cndmask sweep.
__global__ __launch_bounds__(256, 4) void knn_kernel(const float* __restrict__ x,
                                                     const float* __restrict__ xx,
                                                     int* __restrict__ idxout, int C) {
    __shared__ float pdl[BROWS][NN];      // 32 KB
    __shared__ float ctrT[128][KROWS];    // [c][r] for all 8 rows
    __shared__ float xns[KROWS];

    int blk = blockIdx.x;
    int b = blk / (NN / KROWS);
    int rbase = (blk % (NN / KROWS)) * KROWS;
    int tid = threadIdx.x;
    const float* xb = x + (size_t)b * C * NN;

    for (int i = tid; i < C * KROWS; i += 256) {
        int c = i >> 3, r = i & 7;
        ctrT[c][r] = xb[(size_t)c * NN + rbase + r];
    }
    if (tid < KROWS) xns[tid] = xx[b * NN + rbase + tid];
    __syncthreads();

    int w = tid >> 6, lane = tid & 63;

    for (int bat = 0; bat < 2; ++bat) {
        // ---- pd phase: 4 rows x 2048 cols ----
        for (int pass = 0; pass < 2; ++pass) {
            int m0 = pass * 1024 + tid * 4;
            float acc[BROWS][4];
            #pragma unroll
            for (int r = 0; r < BROWS; ++r)
                #pragma unroll
                for (int j = 0; j < 4; ++j) acc[r][j] = 0.f;

            f32x4 xv = *(const f32x4*)(xb + m0);           // c = 0
            for (int c = 0; c + 1 < C; ++c) {
                f32x4 nxt = *(const f32x4*)(xb + (size_t)(c + 1) * NN + m0);
                f32x4 c0 = *(const f32x4*)&ctrT[c][bat * 4];
                #pragma unroll
                for (int j = 0; j < 4; ++j) {
                    acc[0][j] += c0.x * xv[j];
                    acc[1][j] += c0.y * xv[j];
                    acc[2][j] += c0.z * xv[j];
                    acc[3][j] += c0.w * xv[j];
                }
                xv = nxt;
            }
            {
                f32x4 c0 = *(const f32x4*)&ctrT[C - 1][bat * 4];
                #pragma unroll
                for (int j = 0; j < 4; ++j) {
                    acc[0][j] += c0.x * xv[j];
                    acc[1][j] += c0.y * xv[j];
                    acc[2][j] += c0.z * xv[j];
                    acc[3][j] += c0.w * xv[j];
                }
            }
            f32x4 xm = *(const f32x4*)(xx + (size_t)b * NN + m0);
            #pragma unroll
            for (int r = 0; r < BROWS; ++r) {
                f32x4 out;
                #pragma unroll
                for (int j = 0; j < 4; ++j)
                    out[j] = 2.f * acc[r][j] - xns[bat * 4 + r] - xm[j];
                *(f32x4*)&pdl[r][m0] = out;
            }
        }
        __syncthreads();

        // ---- register tournament top-K: wave w owns row (bat*4 + w) ----
        {
            size_t rowglob = (size_t)b * NN + rbase + bat * 4 + w;
            const float* prow = pdl[w];
            int base = lane * 32;

            // slot base (mem word offset within this lane's 32 elems) per reg group;
            // rotation by lane spreads the wave across all banks (8-cy data floor).
            int sb[8];
            #pragma unroll
            for (int i = 0; i < 8; ++i) sb[i] = ((i + lane) & 7) * 4;

            // load 32 elements; DESTINATION index compile-time, address swizzled
            f32x4 el[8];
            #pragma unroll
            for (int i = 0; i < 8; ++i)
                el[i] = *(const f32x4*)&prow[base + sb[i]];

            // local argmax (value, mem-index) with exact lowest-index tie-break
            float lv; int lmj;
            auto rebuild = [&]() {
                float gv[8]; int gj[8];
                #pragma unroll
                for (int i = 0; i < 8; ++i) {
                    f32x4 e = el[i];
                    float v0 = e.x; int j0 = 0;
                    if (e.y > v0) { v0 = e.y; j0 = 1; }
                    if (e.z > v0) { v0 = e.z; j0 = 2; }
                    if (e.w > v0) { v0 = e.w; j0 = 3; }
                    gv[i] = v0; gj[i] = sb[i] + j0;
                }
                #pragma unroll
                for (int step = 4; step >= 1; step >>= 1)
                    #pragma unroll
                    for (int i = 0; i < step; ++i) {
                        bool t = gv[i + step] > gv[i] ||
                                 (gv[i + step] == gv[i] && gj[i + step] < gj[i]);
                        gv[i] = t ? gv[i + step] : gv[i];
                        gj[i] = t ? gj[i + step] : gj[i];
                    }
                lv = gv[0]; lmj = gj[0];
            };
            rebuild();

            int myidx = 0;
            #pragma unroll 1
            for (int k = 0; k < KK; ++k) {
                unsigned long long key =
                    ((unsigned long long)mono(lv) << 32) | (unsigned)(~(base + lmj));
                #pragma unroll
                for (int d = 1; d < 64; d <<= 1) {
                    unsigned long long o = __shfl_xor(key, d, 64);
                    key = (o > key) ? o : key;
                }
                int gi = ~(unsigned)(key & 0xFFFFFFFFull);
                if (lane == k) myidx = gi;
                if ((gi >> 5) == lane) {
                    int memj = gi & 31;
                    int ri = ((memj >> 2) - lane) & 7;   // reg group holding it
                    int q = ri * 4 + (memj & 3);         // flat reg index 0..31
                    #pragma unroll
                    for (int i = 0; i < 8; ++i)
                        #pragma unroll
                        for (int j = 0; j < 4; ++j)
                            el[i][j] = (i * 4 + j == q) ? -FLT_MAX : el[i][j];
                    rebuild();
                }
            }
            if (lane < KK) idxout[rowglob * KK + lane] = myidx;
        }
        __syncthreads();   // pdl reused by next batch
    }
}

// ---------------- P/Q GEMM: Pt/Qt[b][n][o], register-blocked 8o x 4n ----------------
__global__ __launch_bounds__(256) void pq_gemm_kernel(const float* __restrict__ x,
                                                      const float* __restrict__ w,
                                                      float* __restrict__ Pt, float* __restrict__ Qt,
                                                      int C, int Cout) {
    __shared__ float wPT[128][8];
    __shared__ float wQT[128][8];
    int blk = blockIdx.x;            // ((b*(Cout/8)+og)*2 + pass)
    int pass = blk & 1;
    int rest = blk >> 1;
    int nog = Cout >> 3;
    int b = rest / nog;
    int obase = (rest % nog) * 8;
    int tid = threadIdx.x;
    const float* xb = x + (size_t)b * C * NN;

    for (int i = tid; i < C * 8; i += 256) {
        int c = i >> 3, r = i & 7;
        wPT[c][r] = w[(size_t)(obase + r) * 2 * C + c];
        wQT[c][r] = w[(size_t)(obase + r) * 2 * C + C + c];
    }
    __syncthreads();

    int m0 = pass * 1024 + tid * 4;
    float aP[8][4], aQ[8][4];
    #pragma unroll
    for (int r = 0; r < 8; ++r)
        #pragma unroll
        for (int j = 0; j < 4; ++j) { aP[r][j] = 0.f; aQ[r][j] = 0.f; }

    for (int c = 0; c < C; ++c) {
        f32x4 xv = *(const f32x4*)(xb + (size_t)c * NN + m0);
        f32x4 p0 = *(const f32x4*)&wPT[c][0];
        f32x4 p1 = *(const f32x4*)&wPT[c][4];
        f32x4 q0 = *(const f32x4*)&wQT[c][0];
        f32x4 q1 = *(const f32x4*)&wQT[c][4];
        #pragma unroll
        for (int j = 0; j < 4; ++j) {
            aP[0][j] += p0.x * xv[j]; aP[1][j] += p0.y * xv[j];
            aP[2][j] += p0.z * xv[j]; aP[3][j] += p0.w * xv[j];
            aP[4][j] += p1.x * xv[j]; aP[5][j] += p1.y * xv[j];
            aP[6][j] += p1.z * xv[j]; aP[7][j] += p1.w * xv[j];
            aQ[0][j] += q0.x * xv[j]; aQ[1][j] += q0.y * xv[j];
            aQ[2][j] += q0.z * xv[j]; aQ[3][j] += q0.w * xv[j];
            aQ[4][j] += q1.x * xv[j]; aQ[5][j] += q1.y * xv[j];
            aQ[6][j] += q1.z * xv[j]; aQ[7][j] += q1.w * xv[j];
        }
    }
    #pragma unroll
    for (int j = 0; j < 4; ++j) {
        size_t base = ((size_t)b * NN + m0 + j) * Cout + obase;
        f32x4 vP0, vP1, vQ0, vQ1;
        #pragma unroll
        for (int r = 0; r < 4; ++r) { vP0[r] = aP[r][j]; vP1[r] = aP[r + 4][j];
                                      vQ0[r] = aQ[r][j]; vQ1[r] = aQ[r + 4][j]; }
        *(f32x4*)&Pt[base] = vP0; *(f32x4*)&Pt[base + 4] = vP1;
        *(f32x4*)&Qt[base] = vQ0; *(f32x4*)&Qt[base + 4] = vQ1;
    }
}

// ---------------- edge max + feature emit (f32 [c][n] and bf16 hi/lo [n][c]) ----------------
__global__ __launch_bounds__(256) void edge_max_kernel(const float* __restrict__ Pt,
                                                       const float* __restrict__ Qt,
                                                       const int* __restrict__ idx,
                                                       const float* __restrict__ g,
                                                       const float* __restrict__ bt,
                                                       float* __restrict__ xf32,
                                                       unsigned short* __restrict__ Fhi,
                                                       unsigned short* __restrict__ Flo,
                                                       int coff, int Cout) {
    __shared__ int lidx[16][KK];
    int blk = blockIdx.x;
    int b = blk / (NN / 16);
    int nbase = (blk % (NN / 16)) * 16;
    int tid = threadIdx.x;

    for (int i = tid; i < 16 * KK; i += 256) {
        int ns = i / KK, k = i % KK;
        lidx[ns][k] = idx[((size_t)(b * NN + nbase + ns)) * KK + k];
    }
    __syncthreads();

    int oi = tid & 15, nsub = tid >> 4;
    int n = nbase + nsub;
    for (int obase = 0; obase < Cout; obase += 16) {
        int o = obase + oi;
        size_t rowbase = ((size_t)(b * NN + n)) * Cout + o;
        float Pn = Pt[rowbase], Qn = Qt[rowbase];
        float off = Qn - Pn;
        float sc = g[o] * BN_INV_F;
        float bs = bt[o];
        float mx = -FLT_MAX;
        #pragma unroll 4
        for (int k = 0; k < KK; ++k) {
            int m = lidx[nsub][k];
            float pv = Pt[((size_t)(b * NN + m)) * Cout + o];
            float y = sc * (pv + off) + bs;
            y = (y >= 0.f) ? y : 0.2f * y;
            mx = fmaxf(mx, y);
        }
        if (xf32) xf32[((size_t)b * Cout + o) * NN + n] = mx;
        size_t fb = ((size_t)b * NN + n) * 512 + coff + o;
        unsigned short h = f2bf(mx);
        Fhi[fb] = h;
        Flo[fb] = f2bf(mx - bf2f(h));
    }
}

// ---------------- conv (1024x512) via split-bf16 MFMA + fused pooling ----------------
// A = [Whi|Whi|Wlo] (K=1536), B = [Fhi;Flo;Fhi]. 128x128 tile, 4 waves.
__global__ __launch_bounds__(256) void conv_mfma_kernel(const unsigned short* __restrict__ Whi,
                                                        const unsigned short* __restrict__ Wlo,
                                                        const unsigned short* __restrict__ Fhi,
                                                        const unsigned short* __restrict__ Flo,
                                                        const float* __restrict__ gc,
                                                        const float* __restrict__ bc,
                                                        float* __restrict__ pmax,
                                                        float* __restrict__ psum) {
    __shared__ unsigned short As[128 * 64] __attribute__((aligned(16)));  // [o][k] swizzled
    __shared__ unsigned short Bs[128 * 64] __attribute__((aligned(16)));  // [n][k] swizzled

    int blk = blockIdx.x;             // b*128 + ot*16 + nt
    int nt = blk & 15, ot = (blk >> 4) & 7, b = blk >> 7;
    int obase = ot * 128, nbase = nt * 128;
    int tid = threadIdx.x, lane = tid & 63, wid = tid >> 6;
    int wo = wid >> 1, wn = wid & 1;

    f32x4 acc[4][4];
    #pragma unroll
    for (int m = 0; m < 4; ++m)
        #pragma unroll
        for (int q = 0; q < 4; ++q) acc[m][q] = (f32x4){0.f, 0.f, 0.f, 0.f};

    int srow = tid >> 1, sb = (tid & 1) * 4;

    for (int kt = 0; kt < 24; ++kt) {
        int seg = kt >> 3;
        int kc = (kt & 7) * 64;
        const unsigned short* Asrc = ((seg == 2) ? Wlo : Whi) + (size_t)obase * 512 + kc;
        const unsigned short* Bsrc = ((seg == 1) ? Flo : Fhi) + ((size_t)b * NN + nbase) * 512 + kc;
        __syncthreads();
        #pragma unroll
        for (int s = 0; s < 4; ++s) {
            int slot = sb + s;
            uint4 av = *(const uint4*)(Asrc + (size_t)srow * 512 + slot * 8);
            *(uint4*)(As + srow * 64 + ((slot ^ (srow & 7)) * 8)) = av;
            uint4 bv = *(const uint4*)(Bsrc + (size_t)srow * 512 + slot * 8);
            *(uint4*)(Bs + srow * 64 + ((slot ^ (srow & 7)) * 8)) = bv;
        }
        __syncthreads();
        #pragma unroll
        for (int ks = 0; ks < 2; ++ks) {
            s16x8 af[4], bf[4];
            #pragma unroll
            for (int m = 0; m < 4; ++m) {
                int r = wo * 64 + m * 16 + (lane & 15);
                int slot = (ks * 4 + (lane >> 4)) ^ (r & 7);
                af[m] = *(const s16x8*)(As + r * 64 + slot * 8);
                int r2 = wn * 64 + m * 16 + (lane & 15);
                int slot2 = (ks * 4 + (lane >> 4)) ^ (r2 & 7);
                bf[m] = *(const s16x8*)(Bs + r2 * 64 + slot2 * 8);
            }
            #pragma unroll
            for (int m = 0; m < 4; ++m)
                #pragma unroll
                for (int q = 0; q < 4; ++q)
                    acc[m][q] = __builtin_amdgcn_mfma_f32_16x16x32_bf16(af[m], bf[q], acc[m][q], 0, 0, 0);
        }
    }

    __syncthreads();
    float* redm = (float*)As;         // [wn*128 + olocal]
    float* reds = redm + 256;
    #pragma unroll
    for (int m = 0; m < 4; ++m) {
        #pragma unroll
        for (int rg = 0; rg < 4; ++rg) {
            int olocal = wo * 64 + m * 16 + (lane >> 4) * 4 + rg;
            int o = obase + olocal;
            float scv = gc[o] * BN_INV_F, bsv = bc[o];
            float mx = -FLT_MAX, sm = 0.f;
            #pragma unroll
            for (int q = 0; q < 4; ++q) {
                float y = scv * acc[m][q][rg] + bsv;
                y = (y >= 0.f) ? y : 0.2f * y;
                mx = fmaxf(mx, y);
                sm += y;
            }
            #pragma unroll
            for (int d = 1; d < 16; d <<= 1) {
                mx = fmaxf(mx, __shfl_xor(mx, d, 64));
                sm += __shfl_xor(sm, d, 64);
            }
            if ((lane & 15) == 0) {
                redm[wn * 128 + olocal] = mx;
                reds[wn * 128 + olocal] = sm;
            }
        }
    }
    __syncthreads();
    if (tid < 128) {
        float mx = fmaxf(redm[tid], redm[128 + tid]);
        float sm = reds[tid] + reds[128 + tid];
        size_t base = ((size_t)b * 1024 + obase + tid) * 16 + nt;
        pmax[base] = mx;
        psum[base] = sm;
    }
}

__global__ void pool_reduce_kernel(const float* __restrict__ pmax, const float* __restrict__ psum,
                                   float* __restrict__ x56) {
    int t = blockIdx.x * blockDim.x + threadIdx.x;
    if (t >= BB * 1024) return;
    int b = t >> 10, o = t & 1023;
    float mx = -FLT_MAX, sm = 0.f;
    for (int ch = 0; ch < 16; ++ch) {
        mx = fmaxf(mx, pmax[(size_t)t * 16 + ch]);
        sm += psum[(size_t)t * 16 + ch];
    }
    x56[(size_t)b * 2048 + o] = mx;
    x56[(size_t)b * 2048 + 1024 + o] = sm * (1.0f / 2048.0f);
}

// ---------------- FC: one wave per (b,o) ----------------
__global__ void fc_kernel(const float* __restrict__ in, const float* __restrict__ w,
                          const float* __restrict__ bw, const float* __restrict__ g,
                          const float* __restrict__ bt, float* __restrict__ out,
                          int Cin, int Cout, int mode) {
    int gt = blockIdx.x * blockDim.x + threadIdx.x;
    int wid = gt >> 6;
    int lane = threadIdx.x & 63;
    if (wid >= BB * Cout) return;
    int b = wid / Cout, o = wid % Cout;
    const float* ib = in + (size_t)b * Cin;
    const float* wr = w + (size_t)o * Cin;
    float acc = 0.f;
    for (int c = lane; c < Cin; c += 64) acc += ib[c] * wr[c];
    for (int d = 32; d >= 1; d >>= 1) acc += __shfl_down(acc, d, 64);
    if (lane == 0) {
        float y;
        if (mode == 0)      { y = g[o] * acc * BN_INV_F + bt[o]; y = (y >= 0.f) ? y : 0.2f * y; }
        else if (mode == 1) { float h = acc + bw[o]; y = g[o] * h * BN_INV_F + bt[o]; y = (y >= 0.f) ? y : 0.2f * y; }
        else                { y = acc + bw[o]; }
        out[(size_t)b * Cout + o] = y;
    }
}

extern "C" void kernel_launch(void* const* d_in, const int* in_sizes, int n_in,
                              void* d_out, int out_size, void* d_ws, size_t ws_size,
                              hipStream_t stream) {
    const float* x    = (const float*)d_in[0];
    const float* w1   = (const float*)d_in[1];
    const float* g1   = (const float*)d_in[2];
    const float* b1   = (const float*)d_in[3];
    const float* w2   = (const float*)d_in[4];
    const float* g2   = (const float*)d_in[5];
    const float* b2   = (const float*)d_in[6];
    const float* w3   = (const float*)d_in[7];
    const float* g3   = (const float*)d_in[8];
    const float* b3   = (const float*)d_in[9];
    const float* w4   = (const float*)d_in[10];
    const float* g4   = (const float*)d_in[11];
    const float* b4   = (const float*)d_in[12];
    const float* wc   = (const float*)d_in[13];
    const float* gc   = (const float*)d_in[14];
    const float* bc   = (const float*)d_in[15];
    const float* wf1  = (const float*)d_in[16];
    const float* gf1  = (const float*)d_in[17];
    const float* bf1  = (const float*)d_in[18];
    const float* wf2  = (const float*)d_in[19];
    const float* bwf2 = (const float*)d_in[20];
    const float* gf2  = (const float*)d_in[21];
    const float* bf2  = (const float*)d_in[22];
    const float* wf3  = (const float*)d_in[23];
    const float* bwf3 = (const float*)d_in[24];

    char* ws = (char*)d_ws;
    size_t off = 0;
    auto alloc = [&](size_t nbytes) {
        char* p = ws + off;
        off += (nbytes + 255) & ~(size_t)255;
        return p;
    };
    float* xx   = (float*)alloc((size_t)BB * NN * 4);
    int*   idx  = (int*)  alloc((size_t)BB * NN * KK * 4);
    float* Pt   = (float*)alloc((size_t)BB * NN * 256 * 4);
    float* Qt   = (float*)alloc((size_t)BB * NN * 256 * 4);
    float* x1   = (float*)alloc((size_t)BB * 64 * NN * 4);
    float* x2   = (float*)alloc((size_t)BB * 64 * NN * 4);
    float* x3   = (float*)alloc((size_t)BB * 128 * NN * 4);
    unsigned short* Fhi = (unsigned short*)alloc((size_t)BB * NN * 512 * 2);
    unsigned short* Flo = (unsigned short*)alloc((size_t)BB * NN * 512 * 2);
    unsigned short* Whi = (unsigned short*)alloc((size_t)1024 * 512 * 2);
    unsigned short* Wlo = (unsigned short*)alloc((size_t)1024 * 512 * 2);
    float* pmax = (float*)alloc((size_t)BB * 1024 * 16 * 4);
    float* psum = (float*)alloc((size_t)BB * 1024 * 16 * 4);
    float* x56  = (float*)alloc((size_t)BB * 2048 * 4);
    float* f1   = (float*)alloc((size_t)BB * 512 * 4);
    float* f2   = (float*)alloc((size_t)BB * 256 * 4);

    split_kernel<<<(1024 * 512 + 255) / 256, 256, 0, stream>>>(wc, Whi, Wlo, 1024 * 512);

    struct Layer { const float* xin; int C; const float* w; const float* g; const float* bt;
                   float* xout; int Cout; int coff; };
    Layer L[4] = {
        { x,  3,   w1, g1, b1, x1,      64,  0   },
        { x1, 64,  w2, g2, b2, x2,      64,  64  },
        { x2, 64,  w3, g3, b3, x3,      128, 128 },
        { x3, 128, w4, g4, b4, nullptr, 256, 256 },
    };

    for (int l = 0; l < 4; ++l) {
        sqnorm_kernel<<<(BB * NN) / 256, 256, 0, stream>>>(L[l].xin, xx, L[l].C);
        knn_kernel<<<BB * (NN / KROWS), 256, 0, stream>>>(L[l].xin, xx, idx, L[l].C);
        pq_gemm_kernel<<<BB * (L[l].Cout / 8) * 2, 256, 0, stream>>>(L[l].xin, L[l].w, Pt, Qt, L[l].C, L[l].Cout);
        edge_max_kernel<<<BB * (NN / 16), 256, 0, stream>>>(Pt, Qt, idx, L[l].g, L[l].bt,
                                                            L[l].xout, Fhi, Flo, L[l].coff, L[l].Cout);
    }

    conv_mfma_kernel<<<BB * 8 * 16, 256, 0, stream>>>(Whi, Wlo, Fhi, Flo, gc, bc, pmax, psum);
    pool_reduce_kernel<<<(BB * 1024 + 255) / 256, 256, 0, stream>>>(pmax, psum, x56);
    fc_kernel<<<(BB * 512 * 64 + 255) / 256, 256, 0, stream>>>(x56, wf1, nullptr, gf1, bf1, f1, 2048, 512, 0);
    fc_kernel<<<(BB * 256 * 64 + 255) / 256, 256, 0, stream>>>(f1, wf2, bwf2, gf2, bf2, f2, 512, 256, 1);
    fc_kernel<<<(BB * 40 * 64 + 255) / 256, 256, 0, stream>>>(f2, wf3, bwf3, nullptr, nullptr, (float*)d_out, 256, 40, 2);
}

// Round 7
// 1160.433 us; speedup vs baseline: 1.1726x; 1.1726x over previous
//
#include <hip/hip_runtime.h>
#include <hip/hip_bf16.h>
#include <float.h>

#define BB 8
#define NN 2048
#define KK 20
#define KROWS 8
#define BROWS 4   // rows per extraction batch (pdl resident)

static constexpr float BN_INV_F = 0.9999950000374997f;  // 1/sqrt(1+1e-5)

typedef __attribute__((ext_vector_type(4))) float f32x4;
typedef __attribute__((ext_vector_type(8))) short s16x8;

__device__ __forceinline__ unsigned short f2bf(float f) {
    __hip_bfloat16 h = __float2bfloat16(f);
    return __builtin_bit_cast(unsigned short, h);
}
__device__ __forceinline__ float bf2f(unsigned short u) {
    unsigned int v = ((unsigned int)u) << 16;
    return __builtin_bit_cast(float, v);
}
// monotone f32 -> u32 (order-preserving for all finite floats)
__device__ __forceinline__ unsigned mono(float f) {
    unsigned b = __builtin_bit_cast(unsigned, f);
    return b ^ (unsigned)(((int)b >> 31) | 0x80000000);
}

// ---------------- split f32 -> bf16 hi/lo ----------------
__global__ void split_kernel(const float* __restrict__ w, unsigned short* __restrict__ hi,
                             unsigned short* __restrict__ lo, int n) {
    int t = blockIdx.x * blockDim.x + threadIdx.x;
    if (t >= n) return;
    float v = w[t];
    unsigned short h = f2bf(v);
    hi[t] = h;
    lo[t] = f2bf(v - bf2f(h));
}

// ---------------- squared norms: xx[b][n] = sum_c x[b][c][n]^2 ----------------
__global__ void sqnorm_kernel(const float* __restrict__ x, float* __restrict__ xx, int C) {
    int t = blockIdx.x * blockDim.x + threadIdx.x;
    if (t >= BB * NN) return;
    int b = t / NN, n = t % NN;
    const float* xb = x + (size_t)b * C * NN + n;
    float s = 0.f;
    for (int c = 0; c < C; ++c) {
        float v = xb[(size_t)c * NN];
        s += v * v;
    }
    xx[t] = s;
}

// ---------------- kNN: top-K of pd[n][m] = 2*inner - xx[n] - xx[m] ----------------
// pd phase: thread = 4 rows x 4 cols register block (2 batches of 4 rows).
// extraction: one wave per row. Each lane packs its 32 elements into u64 keys
// (mono(v)<<32 | ~idx), bitonic-sorts them in registers (compile-time indices),
// spills sorted top-20 to an LDS list. Per k: branchless 6-step u64 butterfly,
// winner advances its list pointer, ALL lanes refill cur with one ds_read_b64.
__global__ __launch_bounds__(256, 3) void knn_kernel(const float* __restrict__ x,
                                                     const float* __restrict__ xx,
                                                     int* __restrict__ idxout, int C) {
    // union region: pd rows (4*2048 f32 = 32 KB) THEN per-wave sorted lists
    // (4 waves * 20 slots * 64 lanes * u64 = 40 KB). Time-shared with barriers.
    __shared__ unsigned long long ubuf[BROWS * 20 * 64];   // 40960 B
    __shared__ float ctrT[128][KROWS];                     // [c][r] for all 8 rows
    __shared__ float xns[KROWS];

    float* pdlf = (float*)ubuf;

    int blk = blockIdx.x;
    int b = blk / (NN / KROWS);
    int rbase = (blk % (NN / KROWS)) * KROWS;
    int tid = threadIdx.x;
    const float* xb = x + (size_t)b * C * NN;

    for (int i = tid; i < C * KROWS; i += 256) {
        int c = i >> 3, r = i & 7;
        ctrT[c][r] = xb[(size_t)c * NN + rbase + r];
    }
    if (tid < KROWS) xns[tid] = xx[b * NN + rbase + tid];
    __syncthreads();

    int w = tid >> 6, lane = tid & 63;

    for (int bat = 0; bat < 2; ++bat) {
        // ---- pd phase: 4 rows x 2048 cols ----
        for (int pass = 0; pass < 2; ++pass) {
            int m0 = pass * 1024 + tid * 4;
            float acc[BROWS][4];
            #pragma unroll
            for (int r = 0; r < BROWS; ++r)
                #pragma unroll
                for (int j = 0; j < 4; ++j) acc[r][j] = 0.f;

            f32x4 xv = *(const f32x4*)(xb + m0);           // c = 0
            for (int c = 0; c + 1 < C; ++c) {
                f32x4 nxt = *(const f32x4*)(xb + (size_t)(c + 1) * NN + m0);
                f32x4 c0 = *(const f32x4*)&ctrT[c][bat * 4];
                #pragma unroll
                for (int j = 0; j < 4; ++j) {
                    acc[0][j] += c0.x * xv[j];
                    acc[1][j] += c0.y * xv[j];
                    acc[2][j] += c0.z * xv[j];
                    acc[3][j] += c0.w * xv[j];
                }
                xv = nxt;
            }
            {
                f32x4 c0 = *(const f32x4*)&ctrT[C - 1][bat * 4];
                #pragma unroll
                for (int j = 0; j < 4; ++j) {
                    acc[0][j] += c0.x * xv[j];
                    acc[1][j] += c0.y * xv[j];
                    acc[2][j] += c0.z * xv[j];
                    acc[3][j] += c0.w * xv[j];
                }
            }
            f32x4 xm = *(const f32x4*)(xx + (size_t)b * NN + m0);
            #pragma unroll
            for (int r = 0; r < BROWS; ++r) {
                f32x4 out;
                #pragma unroll
                for (int j = 0; j < 4; ++j)
                    out[j] = 2.f * acc[r][j] - xns[bat * 4 + r] - xm[j];
                *(f32x4*)&pdlf[r * NN + m0] = out;
            }
        }
        __syncthreads();   // pd rows complete

        // ---- load + pack this wave's row into u64 keys (all reg, static idx) ----
        int base = lane * 32;
        unsigned long long key[32];
        #pragma unroll
        for (int i = 0; i < 8; ++i) {
            f32x4 e = *(const f32x4*)&pdlf[w * NN + base + i * 4];
            #pragma unroll
            for (int j = 0; j < 4; ++j)
                key[i * 4 + j] = ((unsigned long long)mono(e[j]) << 32)
                               | (unsigned)~(base + i * 4 + j);
        }
        __syncthreads();   // all reads of pd region done before list writes

        // ---- bitonic sort descending, 32 u64 keys, compile-time indices ----
        #pragma unroll
        for (int kk = 2; kk <= 32; kk <<= 1)
            #pragma unroll
            for (int j = kk >> 1; j > 0; j >>= 1)
                #pragma unroll
                for (int i = 0; i < 32; ++i) {
                    int l = i ^ j;
                    if (l > i) {
                        bool up = (i & kk) == 0;             // descending run
                        unsigned long long a = key[i], c2 = key[l];
                        bool sw = up ? (a < c2) : (a > c2);
                        key[i] = sw ? c2 : a;
                        key[l] = sw ? a : c2;
                    }
                }

        // ---- spill sorted top-20 to LDS list (slot-major: conflict-free refill) ----
        unsigned long long* listp = ubuf + (size_t)w * 20 * 64 + lane;
        #pragma unroll
        for (int s = 0; s < 20; ++s)
            listp[s * 64] = key[s];
        __syncthreads();   // lists visible (also orders vs other waves)

        // ---- branchless top-K extraction ----
        {
            size_t rowglob = (size_t)b * NN + rbase + bat * 4 + w;
            unsigned long long cur = key[0];
            int wins = 0, myidx = 0;
            #pragma unroll 1
            for (int k2 = 0; k2 < KK; ++k2) {
                unsigned long long m = cur;
                #pragma unroll
                for (int d = 1; d < 64; d <<= 1) {
                    unsigned long long o = __shfl_xor(m, d, 64);
                    m = (o > m) ? o : m;
                }
                if (lane == k2) myidx = ~(unsigned)(m & 0xFFFFFFFFull);
                wins += (cur == m);
                int slot = (wins < 19) ? wins : 19;
                cur = listp[slot * 64];
            }
            if (lane < KK) idxout[rowglob * KK + lane] = myidx;
        }
        __syncthreads();   // before next batch's pd overwrites the union region
    }
}

// ---------------- P/Q GEMM: Pt/Qt[b][n][o], register-blocked 8o x 4n ----------------
__global__ __launch_bounds__(256) void pq_gemm_kernel(const float* __restrict__ x,
                                                      const float* __restrict__ w,
                                                      float* __restrict__ Pt, float* __restrict__ Qt,
                                                      int C, int Cout) {
    __shared__ float wPT[128][8];
    __shared__ float wQT[128][8];
    int blk = blockIdx.x;            // ((b*(Cout/8)+og)*2 + pass)
    int pass = blk & 1;
    int rest = blk >> 1;
    int nog = Cout >> 3;
    int b = rest / nog;
    int obase = (rest % nog) * 8;
    int tid = threadIdx.x;
    const float* xb = x + (size_t)b * C * NN;

    for (int i = tid; i < C * 8; i += 256) {
        int c = i >> 3, r = i & 7;
        wPT[c][r] = w[(size_t)(obase + r) * 2 * C + c];
        wQT[c][r] = w[(size_t)(obase + r) * 2 * C + C + c];
    }
    __syncthreads();

    int m0 = pass * 1024 + tid * 4;
    float aP[8][4], aQ[8][4];
    #pragma unroll
    for (int r = 0; r < 8; ++r)
        #pragma unroll
        for (int j = 0; j < 4; ++j) { aP[r][j] = 0.f; aQ[r][j] = 0.f; }

    for (int c = 0; c < C; ++c) {
        f32x4 xv = *(const f32x4*)(xb + (size_t)c * NN + m0);
        f32x4 p0 = *(const f32x4*)&wPT[c][0];
        f32x4 p1 = *(const f32x4*)&wPT[c][4];
        f32x4 q0 = *(const f32x4*)&wQT[c][0];
        f32x4 q1 = *(const f32x4*)&wQT[c][4];
        #pragma unroll
        for (int j = 0; j < 4; ++j) {
            aP[0][j] += p0.x * xv[j]; aP[1][j] += p0.y * xv[j];
            aP[2][j] += p0.z * xv[j]; aP[3][j] += p0.w * xv[j];
            aP[4][j] += p1.x * xv[j]; aP[5][j] += p1.y * xv[j];
            aP[6][j] += p1.z * xv[j]; aP[7][j] += p1.w * xv[j];
            aQ[0][j] += q0.x * xv[j]; aQ[1][j] += q0.y * xv[j];
            aQ[2][j] += q0.z * xv[j]; aQ[3][j] += q0.w * xv[j];
            aQ[4][j] += q1.x * xv[j]; aQ[5][j] += q1.y * xv[j];
            aQ[6][j] += q1.z * xv[j]; aQ[7][j] += q1.w * xv[j];
        }
    }
    #pragma unroll
    for (int j = 0; j < 4; ++j) {
        size_t base = ((size_t)b * NN + m0 + j) * Cout + obase;
        f32x4 vP0, vP1, vQ0, vQ1;
        #pragma unroll
        for (int r = 0; r < 4; ++r) { vP0[r] = aP[r][j]; vP1[r] = aP[r + 4][j];
                                      vQ0[r] = aQ[r][j]; vQ1[r] = aQ[r + 4][j]; }
        *(f32x4*)&Pt[base] = vP0; *(f32x4*)&Pt[base + 4] = vP1;
        *(f32x4*)&Qt[base] = vQ0; *(f32x4*)&Qt[base + 4] = vQ1;
    }
}

// ---------------- edge max + feature emit (f32 [c][n] and bf16 hi/lo [n][c]) ----------------
__global__ __launch_bounds__(256) void edge_max_kernel(const float* __restrict__ Pt,
                                                       const float* __restrict__ Qt,
                                                       const int* __restrict__ idx,
                                                       const float* __restrict__ g,
                                                       const float* __restrict__ bt,
                                                       float* __restrict__ xf32,
                                                       unsigned short* __restrict__ Fhi,
                                                       unsigned short* __restrict__ Flo,
                                                       int coff, int Cout) {
    __shared__ int lidx[16][KK];
    int blk = blockIdx.x;
    int b = blk / (NN / 16);
    int nbase = (blk % (NN / 16)) * 16;
    int tid = threadIdx.x;

    for (int i = tid; i < 16 * KK; i += 256) {
        int ns = i / KK, k = i % KK;
        lidx[ns][k] = idx[((size_t)(b * NN + nbase + ns)) * KK + k];
    }
    __syncthreads();

    int oi = tid & 15, nsub = tid >> 4;
    int n = nbase + nsub;
    for (int obase = 0; obase < Cout; obase += 16) {
        int o = obase + oi;
        size_t rowbase = ((size_t)(b * NN + n)) * Cout + o;
        float Pn = Pt[rowbase], Qn = Qt[rowbase];
        float off = Qn - Pn;
        float sc = g[o] * BN_INV_F;
        float bs = bt[o];
        float mx = -FLT_MAX;
        #pragma unroll 4
        for (int k = 0; k < KK; ++k) {
            int m = lidx[nsub][k];
            float pv = Pt[((size_t)(b * NN + m)) * Cout + o];
            float y = sc * (pv + off) + bs;
            y = (y >= 0.f) ? y : 0.2f * y;
            mx = fmaxf(mx, y);
        }
        if (xf32) xf32[((size_t)b * Cout + o) * NN + n] = mx;
        size_t fb = ((size_t)b * NN + n) * 512 + coff + o;
        unsigned short h = f2bf(mx);
        Fhi[fb] = h;
        Flo[fb] = f2bf(mx - bf2f(h));
    }
}

// ---------------- conv (1024x512) via split-bf16 MFMA + fused pooling ----------------
// A = [Whi|Whi|Wlo] (K=1536), B = [Fhi;Flo;Fhi]. 128x128 tile, 4 waves.
__global__ __launch_bounds__(256) void conv_mfma_kernel(const unsigned short* __restrict__ Whi,
                                                        const unsigned short* __restrict__ Wlo,
                                                        const unsigned short* __restrict__ Fhi,
                                                        const unsigned short* __restrict__ Flo,
                                                        const float* __restrict__ gc,
                                                        const float* __restrict__ bc,
                                                        float* __restrict__ pmax,
                                                        float* __restrict__ psum) {
    __shared__ unsigned short As[128 * 64] __attribute__((aligned(16)));  // [o][k] swizzled
    __shared__ unsigned short Bs[128 * 64] __attribute__((aligned(16)));  // [n][k] swizzled

    int blk = blockIdx.x;             // b*128 + ot*16 + nt
    int nt = blk & 15, ot = (blk >> 4) & 7, b = blk >> 7;
    int obase = ot * 128, nbase = nt * 128;
    int tid = threadIdx.x, lane = tid & 63, wid = tid >> 6;
    int wo = wid >> 1, wn = wid & 1;

    f32x4 acc[4][4];
    #pragma unroll
    for (int m = 0; m < 4; ++m)
        #pragma unroll
        for (int q = 0; q < 4; ++q) acc[m][q] = (f32x4){0.f, 0.f, 0.f, 0.f};

    int srow = tid >> 1, sb = (tid & 1) * 4;

    for (int kt = 0; kt < 24; ++kt) {
        int seg = kt >> 3;
        int kc = (kt & 7) * 64;
        const unsigned short* Asrc = ((seg == 2) ? Wlo : Whi) + (size_t)obase * 512 + kc;
        const unsigned short* Bsrc = ((seg == 1) ? Flo : Fhi) + ((size_t)b * NN + nbase) * 512 + kc;
        __syncthreads();
        #pragma unroll
        for (int s = 0; s < 4; ++s) {
            int slot = sb + s;
            uint4 av = *(const uint4*)(Asrc + (size_t)srow * 512 + slot * 8);
            *(uint4*)(As + srow * 64 + ((slot ^ (srow & 7)) * 8)) = av;
            uint4 bv = *(const uint4*)(Bsrc + (size_t)srow * 512 + slot * 8);
            *(uint4*)(Bs + srow * 64 + ((slot ^ (srow & 7)) * 8)) = bv;
        }
        __syncthreads();
        #pragma unroll
        for (int ks = 0; ks < 2; ++ks) {
            s16x8 af[4], bf[4];
            #pragma unroll
            for (int m = 0; m < 4; ++m) {
                int r = wo * 64 + m * 16 + (lane & 15);
                int slot = (ks * 4 + (lane >> 4)) ^ (r & 7);
                af[m] = *(const s16x8*)(As + r * 64 + slot * 8);
                int r2 = wn * 64 + m * 16 + (lane & 15);
                int slot2 = (ks * 4 + (lane >> 4)) ^ (r2 & 7);
                bf[m] = *(const s16x8*)(Bs + r2 * 64 + slot2 * 8);
            }
            #pragma unroll
            for (int m = 0; m < 4; ++m)
                #pragma unroll
                for (int q = 0; q < 4; ++q)
                    acc[m][q] = __builtin_amdgcn_mfma_f32_16x16x32_bf16(af[m], bf[q], acc[m][q], 0, 0, 0);
        }
    }

    __syncthreads();
    float* redm = (float*)As;         // [wn*128 + olocal]
    float* reds = redm + 256;
    #pragma unroll
    for (int m = 0; m < 4; ++m) {
        #pragma unroll
        for (int rg = 0; rg < 4; ++rg) {
            int olocal = wo * 64 + m * 16 + (lane >> 4) * 4 + rg;
            int o = obase + olocal;
            float scv = gc[o] * BN_INV_F, bsv = bc[o];
            float mx = -FLT_MAX, sm = 0.f;
            #pragma unroll
            for (int q = 0; q < 4; ++q) {
                float y = scv * acc[m][q][rg] + bsv;
                y = (y >= 0.f) ? y : 0.2f * y;
                mx = fmaxf(mx, y);
                sm += y;
            }
            #pragma unroll
            for (int d = 1; d < 16; d <<= 1) {
                mx = fmaxf(mx, __shfl_xor(mx, d, 64));
                sm += __shfl_xor(sm, d, 64);
            }
            if ((lane & 15) == 0) {
                redm[wn * 128 + olocal] = mx;
                reds[wn * 128 + olocal] = sm;
            }
        }
    }
    __syncthreads();
    if (tid < 128) {
        float mx = fmaxf(redm[tid], redm[128 + tid]);
        float sm = reds[tid] + reds[128 + tid];
        size_t base = ((size_t)b * 1024 + obase + tid) * 16 + nt;
        pmax[base] = mx;
        psum[base] = sm;
    }
}

__global__ void pool_reduce_kernel(const float* __restrict__ pmax, const float* __restrict__ psum,
                                   float* __restrict__ x56) {
    int t = blockIdx.x * blockDim.x + threadIdx.x;
    if (t >= BB * 1024) return;
    int b = t >> 10, o = t & 1023;
    float mx = -FLT_MAX, sm = 0.f;
    for (int ch = 0; ch < 16; ++ch) {
        mx = fmaxf(mx, pmax[(size_t)t * 16 + ch]);
        sm += psum[(size_t)t * 16 + ch];
    }
    x56[(size_t)b * 2048 + o] = mx;
    x56[(size_t)b * 2048 + 1024 + o] = sm * (1.0f / 2048.0f);
}

// ---------------- FC: one wave per (b,o) ----------------
__global__ void fc_kernel(const float* __restrict__ in, const float* __restrict__ w,
                          const float* __restrict__ bw, const float* __restrict__ g,
                          const float* __restrict__ bt, float* __restrict__ out,
                          int Cin, int Cout, int mode) {
    int gt = blockIdx.x * blockDim.x + threadIdx.x;
    int wid = gt >> 6;
    int lane = threadIdx.x & 63;
    if (wid >= BB * Cout) return;
    int b = wid / Cout, o = wid % Cout;
    const float* ib = in + (size_t)b * Cin;
    const float* wr = w + (size_t)o * Cin;
    float acc = 0.f;
    for (int c = lane; c < Cin; c += 64) acc += ib[c] * wr[c];
    for (int d = 32; d >= 1; d >>= 1) acc += __shfl_down(acc, d, 64);
    if (lane == 0) {
        float y;
        if (mode == 0)      { y = g[o] * acc * BN_INV_F + bt[o]; y = (y >= 0.f) ? y : 0.2f * y; }
        else if (mode == 1) { float h = acc + bw[o]; y = g[o] * h * BN_INV_F + bt[o]; y = (y >= 0.f) ? y : 0.2f * y; }
        else                { y = acc + bw[o]; }
        out[(size_t)b * Cout + o] = y;
    }
}

extern "C" void kernel_launch(void* const* d_in, const int* in_sizes, int n_in,
                              void* d_out, int out_size, void* d_ws, size_t ws_size,
                              hipStream_t stream) {
    const float* x    = (const float*)d_in[0];
    const float* w1   = (const float*)d_in[1];
    const float* g1   = (const float*)d_in[2];
    const float* b1   = (const float*)d_in[3];
    const float* w2   = (const float*)d_in[4];
    const float* g2   = (const float*)d_in[5];
    const float* b2   = (const float*)d_in[6];
    const float* w3   = (const float*)d_in[7];
    const float* g3   = (const float*)d_in[8];
    const float* b3   = (const float*)d_in[9];
    const float* w4   = (const float*)d_in[10];
    const float* g4   = (const float*)d_in[11];
    const float* b4   = (const float*)d_in[12];
    const float* wc   = (const float*)d_in[13];
    const float* gc   = (const float*)d_in[14];
    const float* bc   = (const float*)d_in[15];
    const float* wf1  = (const float*)d_in[16];
    const float* gf1  = (const float*)d_in[17];
    const float* bf1  = (const float*)d_in[18];
    const float* wf2  = (const float*)d_in[19];
    const float* bwf2 = (const float*)d_in[20];
    const float* gf2  = (const float*)d_in[21];
    const float* bf2  = (const float*)d_in[22];
    const float* wf3  = (const float*)d_in[23];
    const float* bwf3 = (const float*)d_in[24];

    char* ws = (char*)d_ws;
    size_t off = 0;
    auto alloc = [&](size_t nbytes) {
        char* p = ws + off;
        off += (nbytes + 255) & ~(size_t)255;
        return p;
    };
    float* xx   = (float*)alloc((size_t)BB * NN * 4);
    int*   idx  = (int*)  alloc((size_t)BB * NN * KK * 4);
    float* Pt   = (float*)alloc((size_t)BB * NN * 256 * 4);
    float* Qt   = (float*)alloc((size_t)BB * NN * 256 * 4);
    float* x1   = (float*)alloc((size_t)BB * 64 * NN * 4);
    float* x2   = (float*)alloc((size_t)BB * 64 * NN * 4);
    float* x3   = (float*)alloc((size_t)BB * 128 * NN * 4);
    unsigned short* Fhi = (unsigned short*)alloc((size_t)BB * NN * 512 * 2);
    unsigned short* Flo = (unsigned short*)alloc((size_t)BB * NN * 512 * 2);
    unsigned short* Whi = (unsigned short*)alloc((size_t)1024 * 512 * 2);
    unsigned short* Wlo = (unsigned short*)alloc((size_t)1024 * 512 * 2);
    float* pmax = (float*)alloc((size_t)BB * 1024 * 16 * 4);
    float* psum = (float*)alloc((size_t)BB * 1024 * 16 * 4);
    float* x56  = (float*)alloc((size_t)BB * 2048 * 4);
    float* f1   = (float*)alloc((size_t)BB * 512 * 4);
    float* f2   = (float*)alloc((size_t)BB * 256 * 4);

    split_kernel<<<(1024 * 512 + 255) / 256, 256, 0, stream>>>(wc, Whi, Wlo, 1024 * 512);

    struct Layer { const float* xin; int C; const float* w; const float* g; const float* bt;
                   float* xout; int Cout; int coff; };
    Layer L[4] = {
        { x,  3,   w1, g1, b1, x1,      64,  0   },
        { x1, 64,  w2, g2, b2, x2,      64,  64  },
        { x2, 64,  w3, g3, b3, x3,      128, 128 },
        { x3, 128, w4, g4, b4, nullptr, 256, 256 },
    };

    for (int l = 0; l < 4; ++l) {
        sqnorm_kernel<<<(BB * NN) / 256, 256, 0, stream>>>(L[l].xin, xx, L[l].C);
        knn_kernel<<<BB * (NN / KROWS), 256, 0, stream>>>(L[l].xin, xx, idx, L[l].C);
        pq_gemm_kernel<<<BB * (L[l].Cout / 8) * 2, 256, 0, stream>>>(L[l].xin, L[l].w, Pt, Qt, L[l].C, L[l].Cout);
        edge_max_kernel<<<BB * (NN / 16), 256, 0, stream>>>(Pt, Qt, idx, L[l].g, L[l].bt,
                                                            L[l].xout, Fhi, Flo, L[l].coff, L[l].Cout);
    }

    conv_mfma_kernel<<<BB * 8 * 16, 256, 0, stream>>>(Whi, Wlo, Fhi, Flo, gc, bc, pmax, psum);
    pool_reduce_kernel<<<(BB * 1024 + 255) / 256, 256, 0, stream>>>(pmax, psum, x56);
    fc_kernel<<<(BB * 512 * 64 + 255) / 256, 256, 0, stream>>>(x56, wf1, nullptr, gf1, bf1, f1, 2048, 512, 0);
    fc_kernel<<<(BB * 256 * 64 + 255) / 256, 256, 0, stream>>>(f1, wf2, bwf2, gf2, bf2, f2, 512, 256, 1);
    fc_kernel<<<(BB * 40 * 64 + 255) / 256, 256, 0, stream>>>(f2, wf3, bwf3, nullptr, nullptr, (float*)d_out, 256, 40, 2);
}